// Round 7
// baseline (5434.037 us; speedup 1.0000x reference)
//
#include <hip/hip_runtime.h>
#include <hip/hip_bf16.h>
#include <stdint.h>

// LSTM T=512 B=64 I=H=1024.
// Phase 1: xg = x @ w_ih^T + (b_ih+b_hh)  -- MFMA GEMM, bf16 out, wave-fragment layout.
// Phase 2: persistent kernel, 512 blocks x 1 wave. Each wave: one batch-group (16) x
//          8 hidden cols, all 4 gates. w_hh in 256 VGPRs, A direct global->reg (sc0 sc1),
//          in-wave LDS gate exchange (no barriers anywhere), epoch-value flags.

typedef short  short8 __attribute__((ext_vector_type(8)));
typedef float  f32x4  __attribute__((ext_vector_type(4)));
typedef int    i32x4  __attribute__((ext_vector_type(4)));

#define T_STEPS 512

__device__ __forceinline__ unsigned short f2bf(float f) {
    uint32_t u = __float_as_uint(f);
    return (unsigned short)((u + 0x7fffu + ((u >> 16) & 1u)) >> 16);
}
__device__ __forceinline__ float bf2f(unsigned short v) {
    return __uint_as_float(((uint32_t)v) << 16);
}
__device__ __forceinline__ float sigf(float x)  { return 1.0f / (1.0f + __expf(-x)); }
__device__ __forceinline__ float tanhf_(float x){ return 1.0f - 2.0f / (__expf(2.0f * x) + 1.0f); }

// ---------------------------------------------------------------- setup
__global__ void k_setup(const float* __restrict__ w_ih,
                        const float* __restrict__ b_ih, const float* __restrict__ b_hh,
                        const float* __restrict__ h0,
                        unsigned short* __restrict__ wb, float* __restrict__ bias,
                        unsigned short* __restrict__ hb0, unsigned* __restrict__ flags) {
    int idx = blockIdx.x * blockDim.x + threadIdx.x;
    int stride = gridDim.x * blockDim.x;
    const float4* w4 = (const float4*)w_ih;
    ushort4* wb4 = (ushort4*)wb;
    for (int i = idx; i < 1048576; i += stride) {       // 4096*1024/4
        float4 v = w4[i];
        wb4[i] = make_ushort4(f2bf(v.x), f2bf(v.y), f2bf(v.z), f2bf(v.w));
    }
    const float4* bi4 = (const float4*)b_ih;
    const float4* bh4 = (const float4*)b_hh;
    float4* bs4 = (float4*)bias;
    for (int i = idx; i < 1024; i += stride) {
        float4 a = bi4[i], b = bh4[i];
        bs4[i] = make_float4(a.x + b.x, a.y + b.y, a.z + b.z, a.w + b.w);
    }
    const float4* h04 = (const float4*)h0;
    ushort4* hb4 = (ushort4*)hb0;
    for (int i = idx; i < 16384; i += stride) {
        float4 v = h04[i];
        hb4[i] = make_ushort4(f2bf(v.x), f2bf(v.y), f2bf(v.z), f2bf(v.w));
    }
    for (int i = idx; i < 512; i += stride) flags[i] = 0u;   // [4][128] epoch flags
}

// ---------------------------------------------------------------- xg GEMM
// out[m][n] = sum_k x[m][k]*w_ih[n][k] + bias[n], m = t*64+batch, n = gate*1024+j.
// xg layout matches k_lstm wave fragments:
//   off = ((((t*4+bg)*64 + jg)*2 + wv)*64 + lane)*8 + p*4 + q
//   lane = kq*16 + gate*4 + jl ; value = (batch bg*16+kq*4+q, gate, col jg*16+wv*8+p*4+jl)
__device__ __forceinline__ short8 lds_frag(const unsigned short* base, int row, int kbyte) {
    unsigned off = (unsigned)(row * 128 + kbyte);
    off ^= (unsigned)((row & 7) << 4);
    return *(const short8*)((const char*)base + off);
}

__global__ __launch_bounds__(256) void k_gemm(const float* __restrict__ x,
                                              const unsigned short* __restrict__ wb,
                                              const float* __restrict__ bias,
                                              unsigned short* __restrict__ xg) {
    __shared__ __align__(16) unsigned short As[128 * 64];
    __shared__ __align__(16) unsigned short Bs[128 * 64];
    unsigned orig = blockIdx.x;
    unsigned xcd = orig & 7, idx = orig >> 3;           // idx 0..1023
    unsigned n_t = xcd * 4 + (idx >> 8);                // 0..31
    unsigned m_t = idx & 255;                           // 0..255
    const int m0 = (int)m_t * 128, n0 = (int)n_t * 128;
    const int tid = threadIdx.x;
    const int lane = tid & 63, w = tid >> 6;
    const int wr = w >> 1, wc = w & 1;
    const int r = lane & 15, kq = lane >> 4;

    f32x4 acc[4][4] = {};

    const int ar = tid >> 1, ah = tid & 1;              // staging row / k-half

    for (int k0 = 0; k0 < 1024; k0 += 64) {
        {
            const float4* src = (const float4*)(x + (size_t)(m0 + ar) * 1024 + k0 + ah * 32);
            unsigned aw_base = (unsigned)(ar * 128 + ah * 64);
            unsigned sw = (unsigned)((ar & 7) << 4);
            #pragma unroll
            for (int i = 0; i < 4; ++i) {
                float4 v0 = src[2 * i], v1 = src[2 * i + 1];
                short8 p;
                p[0] = (short)f2bf(v0.x); p[1] = (short)f2bf(v0.y);
                p[2] = (short)f2bf(v0.z); p[3] = (short)f2bf(v0.w);
                p[4] = (short)f2bf(v1.x); p[5] = (short)f2bf(v1.y);
                p[6] = (short)f2bf(v1.z); p[7] = (short)f2bf(v1.w);
                *(short8*)((char*)As + ((aw_base + i * 16) ^ sw)) = p;
            }
        }
        {
            const short8* src = (const short8*)(wb + (size_t)(n0 + ar) * 1024 + k0 + ah * 32);
            unsigned bw_base = (unsigned)(ar * 128 + ah * 64);
            unsigned sw = (unsigned)((ar & 7) << 4);
            #pragma unroll
            for (int i = 0; i < 4; ++i) {
                short8 p = src[i];
                *(short8*)((char*)Bs + ((bw_base + i * 16) ^ sw)) = p;
            }
        }
        __syncthreads();
        #pragma unroll
        for (int kk = 0; kk < 2; ++kk) {
            short8 af[4], bfr[4];
            #pragma unroll
            for (int i = 0; i < 4; ++i) af[i]  = lds_frag(As, wr * 64 + i * 16 + r, (kk * 32 + kq * 8) * 2);
            #pragma unroll
            for (int j = 0; j < 4; ++j) bfr[j] = lds_frag(Bs, wc * 64 + j * 16 + r, (kk * 32 + kq * 8) * 2);
            #pragma unroll
            for (int i = 0; i < 4; ++i)
                #pragma unroll
                for (int j = 0; j < 4; ++j)
                    acc[i][j] = __builtin_amdgcn_mfma_f32_16x16x32_bf16(af[i], bfr[j], acc[i][j], 0, 0, 0);
        }
        __syncthreads();
    }

    // epilogue: scatter into k_lstm wave-fragment layout
    const int t_idx = (int)m_t * 2 + wr;                // uniform per wave
    #pragma unroll
    for (int j = 0; j < 4; ++j) {
        int nn = n0 + wc * 64 + j * 16 + r;
        float bsum = bias[nn];
        int gate = nn >> 10, jcol = nn & 1023;
        int jgc = jcol >> 4, jloc = jcol & 15;
        int wvc = jloc >> 3, p = (jloc >> 2) & 1, jlc = jloc & 3;
        int lane_c = kq * 16 + gate * 4 + jlc;
        #pragma unroll
        for (int i = 0; i < 4; ++i) {                   // i == bg
            size_t base = ((((size_t)t_idx * 4 + i) * 64 + jgc) * 2 + wvc) * 512
                          + (size_t)lane_c * 8 + p * 4;
            #pragma unroll
            for (int q = 0; q < 4; ++q)
                xg[base + q] = f2bf(acc[i][j][q] + bsum);
        }
    }
}

// ---------------------------------------------------------------- persistent recurrence
// 512 blocks x 64 threads (1 wave each). L: bg = L>>7 (16 batches), widx = L&127,
// jg = widx>>1, wv = widx&1 -> 8 hidden cols (2 tasks of 4), all 4 gates.
#define LA(OFF) asm volatile("global_load_dwordx4 %0, %1, off offset:" #OFF " sc0 sc1" \
                             : "=v"(a[(OFF)/64]) : "v"(ap) : "memory")

__global__ __launch_bounds__(64, 1) void k_lstm(
    const float* __restrict__ w_hh, const float* __restrict__ c0g,
    const unsigned short* __restrict__ xg,
    unsigned short* __restrict__ hbuf,                  // [2][64][1024] bf16
    unsigned* __restrict__ flags,                       // [4][128] epoch values
    float* __restrict__ outH, float* __restrict__ outC) {
    __shared__ float gx[2][16][4][4];                   // [task][row][gate][jl]

    const unsigned L = blockIdx.x;
    const unsigned bg = L >> 7, widx = L & 127;
    const unsigned jg = widx >> 1, wv = widx & 1;
    const int lane = threadIdx.x & 63;
    const int r = lane & 15, kq = lane >> 4;
    const int lg = r >> 2, jl = r & 3;                  // this lane's gate / j-offset

    // ---- pin w_hh fragments: 2 tasks x 32 k-iters x short8 = 256 VGPRs
    short8 bf0[32], bf1[32];
    {
        const int n0 = lg * 1024 + (int)(jg * 16 + wv * 8) + jl;
        const float4* w0p = (const float4*)(w_hh + (size_t)n0 * 1024 + kq * 8);
        const float4* w1p = (const float4*)(w_hh + (size_t)(n0 + 4) * 1024 + kq * 8);
        #pragma unroll
        for (int kit = 0; kit < 32; ++kit) {
            float4 v0 = w0p[kit * 8], v1 = w0p[kit * 8 + 1];
            short8 p;
            p[0] = (short)f2bf(v0.x); p[1] = (short)f2bf(v0.y);
            p[2] = (short)f2bf(v0.z); p[3] = (short)f2bf(v0.w);
            p[4] = (short)f2bf(v1.x); p[5] = (short)f2bf(v1.y);
            p[6] = (short)f2bf(v1.z); p[7] = (short)f2bf(v1.w);
            bf0[kit] = p;
            float4 u0 = w1p[kit * 8], u1 = w1p[kit * 8 + 1];
            short8 qv;
            qv[0] = (short)f2bf(u0.x); qv[1] = (short)f2bf(u0.y);
            qv[2] = (short)f2bf(u0.z); qv[3] = (short)f2bf(u0.w);
            qv[4] = (short)f2bf(u1.x); qv[5] = (short)f2bf(u1.y);
            qv[6] = (short)f2bf(u1.z); qv[7] = (short)f2bf(u1.w);
            bf1[kit] = qv;
        }
    }

    // ---- cell state: lane -> (row kq*4+lg, cols jl and jl+4 of this wave's 8)
    const int grow = (int)bg * 16 + kq * 4 + lg;
    const int col0 = (int)(jg * 16 + wv * 8) + jl;
    const size_t o0 = (size_t)grow * 1024 + col0;
    float c0r = c0g[o0], c1r = c0g[o0 + 4];
    float h0v = 0.f, h1v = 0.f;

    const unsigned arow_off = (unsigned)(((int)bg * 16 + r) * 1024 + kq * 8) * 2u;
    const unsigned* fl = flags + bg * 128u;
    unsigned* myflag = flags + bg * 128u + widx;

    for (int t = 0; t < T_STEPS; ++t) {
        // ---- wait for all 128 producer waves of our bg to finish step t-1
        if (t > 0) {
            const unsigned tt = (unsigned)t;
            while (true) {
                unsigned p0 = __hip_atomic_load(fl + lane, __ATOMIC_RELAXED,
                                                __HIP_MEMORY_SCOPE_AGENT);
                unsigned p1 = __hip_atomic_load(fl + 64 + lane, __ATOMIC_RELAXED,
                                                __HIP_MEMORY_SCOPE_AGENT);
                if (__ballot((p0 >= tt) && (p1 >= tt)) == ~0ull) break;
                __builtin_amdgcn_s_sleep(2);
            }
        }

        // ---- A fragments: 32 x 16B coherent loads, base + immediate offsets
        const char* ap = (const char*)(hbuf + (size_t)(t & 1) * 65536) + arow_off;
        i32x4 a[32];
        LA(0);    LA(64);   LA(128);  LA(192);  LA(256);  LA(320);  LA(384);  LA(448);
        LA(512);  LA(576);  LA(640);  LA(704);  LA(768);  LA(832);  LA(896);  LA(960);
        LA(1024); LA(1088); LA(1152); LA(1216); LA(1280); LA(1344); LA(1408); LA(1472);
        LA(1536); LA(1600); LA(1664); LA(1728); LA(1792); LA(1856); LA(1920); LA(1984);
        // xg fragment (normal cached load), issued last -> hidden under MFMA
        short8 xv = *(const short8*)(xg + ((((size_t)t * 4 + bg) * 64 + jg) * 2 + wv) * 512
                                     + (size_t)lane * 8);
        asm volatile("s_waitcnt vmcnt(1)" ::: "memory");   // all A arrived (xv may fly)
        __builtin_amdgcn_sched_barrier(0);

        // ---- 64 MFMAs, 4 independent chains
        f32x4 ae0 = {0.f,0.f,0.f,0.f}, ao0 = {0.f,0.f,0.f,0.f};
        f32x4 ae1 = {0.f,0.f,0.f,0.f}, ao1 = {0.f,0.f,0.f,0.f};
        #pragma unroll
        for (int kit = 0; kit < 32; kit += 2) {
            short8 av0 = __builtin_bit_cast(short8, a[kit]);
            short8 av1 = __builtin_bit_cast(short8, a[kit + 1]);
            ae0 = __builtin_amdgcn_mfma_f32_16x16x32_bf16(av0, bf0[kit], ae0, 0, 0, 0);
            ae1 = __builtin_amdgcn_mfma_f32_16x16x32_bf16(av0, bf1[kit], ae1, 0, 0, 0);
            ao0 = __builtin_amdgcn_mfma_f32_16x16x32_bf16(av1, bf0[kit + 1], ao0, 0, 0, 0);
            ao1 = __builtin_amdgcn_mfma_f32_16x16x32_bf16(av1, bf1[kit + 1], ao1, 0, 0, 0);
        }
        asm volatile("s_waitcnt vmcnt(0)" ::: "memory");   // xv arrived
        __builtin_amdgcn_sched_barrier(0);
        f32x4 acc0 = ae0 + ao0, acc1 = ae1 + ao1;
        #pragma unroll
        for (int q = 0; q < 4; ++q) {
            acc0[q] += bf2f((unsigned short)xv[q]);
            acc1[q] += bf2f((unsigned short)xv[4 + q]);
        }

        // ---- in-wave gate exchange via LDS (single wave: DS pipe in-order, no barrier)
        #pragma unroll
        for (int q = 0; q < 4; ++q) {
            gx[0][kq * 4 + q][lg][jl] = acc0[q];
            gx[1][kq * 4 + q][lg][jl] = acc1[q];
        }
        __builtin_amdgcn_sched_barrier(0);
        const int rs = kq * 4 + lg;
        float i0 = gx[0][rs][0][jl], fz0 = gx[0][rs][1][jl];
        float g0 = gx[0][rs][2][jl], oz0 = gx[0][rs][3][jl];
        float i1 = gx[1][rs][0][jl], fz1 = gx[1][rs][1][jl];
        float g1 = gx[1][rs][2][jl], oz1 = gx[1][rs][3][jl];

        c0r = sigf(fz0) * c0r + sigf(i0) * tanhf_(g0);
        h0v = sigf(oz0) * tanhf_(c0r);
        c1r = sigf(fz1) * c1r + sigf(i1) * tanhf_(g1);
        h1v = sigf(oz1) * tanhf_(c1r);

        // ---- publish h (2 coherent ushort stores) + epoch flag
        if (t < T_STEPS - 1) {
            unsigned short* hn = hbuf + (size_t)((t + 1) & 1) * 65536;
            unsigned hv0 = f2bf(h0v), hv1 = f2bf(h1v);
            unsigned short* s0p = hn + o0;
            unsigned short* s1p = s0p + 4;
            asm volatile("global_store_short %0, %1, off sc0 sc1"
                         :: "v"(s0p), "v"(hv0) : "memory");
            asm volatile("global_store_short %0, %1, off sc0 sc1"
                         :: "v"(s1p), "v"(hv1) : "memory");
            asm volatile("s_waitcnt vmcnt(0)" ::: "memory");
            __builtin_amdgcn_sched_barrier(0);
            if (lane == 0)
                __hip_atomic_store(myflag, (unsigned)(t + 1),
                                   __ATOMIC_RELAXED, __HIP_MEMORY_SCOPE_AGENT);
        }
    }

    outH[o0] = h0v; outH[o0 + 4] = h1v;
    outC[o0] = c0r; outC[o0 + 4] = c1r;
}

// ---------------------------------------------------------------- launch
extern "C" void kernel_launch(void* const* d_in, const int* in_sizes, int n_in,
                              void* d_out, int out_size, void* d_ws, size_t ws_size,
                              hipStream_t stream) {
    const float* x    = (const float*)d_in[0];
    const float* h0   = (const float*)d_in[1];
    const float* c0   = (const float*)d_in[2];
    const float* w_ih = (const float*)d_in[3];
    const float* w_hh = (const float*)d_in[4];
    const float* b_ih = (const float*)d_in[5];
    const float* b_hh = (const float*)d_in[6];

    float* outH = (float*)d_out;
    float* outC = outH + 65536;

    uint8_t* ws = (uint8_t*)d_ws;
    unsigned short* xg    = (unsigned short*)ws;                         // 268,435,456 B
    unsigned short* wb    = (unsigned short*)(ws + 268435456ULL);        //   8,388,608 B
    float*          bias  = (float*)(ws + 276824064ULL);                 //      16,384 B
    unsigned short* hbuf  = (unsigned short*)(ws + 276840448ULL);        //     262,144 B
    unsigned*       flags = (unsigned*)(ws + 277102592ULL);              //       2,048 B

    k_setup<<<1024, 256, 0, stream>>>(w_ih, b_ih, b_hh, h0, wb, bias, hbuf, flags);
    k_gemm<<<8192, 256, 0, stream>>>(x, wb, bias, xg);
    k_lstm<<<512, 64, 0, stream>>>(w_hh, c0, xg, hbuf, flags, outH, outC);
}